// Round 29
// baseline (730.780 us; speedup 1.0000x reference)
//
#include <hip/hip_runtime.h>
#include <math.h>

#define E_CNT 800000
#define G_CNT 1000000
#define NUM_NODES 100000
#define ROWS 128
#define NT ((G_CNT + ROWS - 1) / ROWS)   // 7813 tiles (last tile clamped)
#define CSTRIDE ((size_t)NT * ROWS)      // compW j-plane stride (1000064)
#define GRID 256                         // 1 persistent block per CU
#define TPB 512                          // 8 waves

typedef __attribute__((ext_vector_type(8))) short bf16x8;    // 8 bf16 = 4 VGPRs
typedef __attribute__((ext_vector_type(4))) float f32x4;
typedef __attribute__((ext_vector_type(16))) float f32x16;

__device__ __forceinline__ short f2bf(float f) {
    union { float f; unsigned u; } v; v.f = f;
    unsigned r = v.u + 0x7fffu + ((v.u >> 16) & 1u);   // RNE
    return (short)(r >> 16);
}

// Prep: degree atomics + W1 transpose only (no emb table — main gathers fp32).
#define PREP_DEG_BLOCKS 3125
#define PREP_W1T_BLOCKS 256
__global__ void prep_fused_kernel(
    const int* __restrict__ ei, float* __restrict__ deg,
    const float* __restrict__ W1, short* __restrict__ w1t)
{
    int b2 = blockIdx.x;
    if (b2 < PREP_DEG_BLOCKS) {
        int e = b2 * 256 + threadIdx.x;
        if (e < E_CNT) {
            atomicAdd(&deg[ei[e]], 1.0f);
            atomicAdd(&deg[ei[E_CNT + e]], 1.0f);
        }
    } else {
        int t = (b2 - PREP_DEG_BLOCKS) * 256 + threadIdx.x;
        int n = t >> 8, k = t & 255;
        w1t[t] = f2bf(W1[k * 256 + n]);
    }
}

// Tail: ss (deg-MLP) + head MLP + sigmoid at full occupancy.
__global__ void tail_kernel(
    const float* __restrict__ compW,   // (8, CSTRIDE)
    const int*   __restrict__ eg,
    const int*   __restrict__ ei,
    const float* __restrict__ deg,
    const float* __restrict__ Ws1, const float* __restrict__ bs1,
    const float* __restrict__ Ws2, const float* __restrict__ bs2,
    const float* __restrict__ Wc1, const float* __restrict__ bc1,
    const float* __restrict__ Wc2, const float* __restrict__ bc2,
    float* __restrict__ out)
{
    int g = blockIdx.x * blockDim.x + threadIdx.x;
    if (g >= G_CNT) return;
    int2 gg = ((const int2*)eg)[g];
    float s0 = deg[ei[gg.x]];
    float s1 = deg[ei[E_CNT + gg.x]];
    float s2 = deg[ei[gg.y]];
    float s3 = deg[ei[E_CNT + gg.y]];
    float cc[8];
    #pragma unroll
    for (int a = 0; a < 8; ++a) cc[a] = compW[a * CSTRIDE + g];

    float ss = bs2[0];
    #pragma unroll 8
    for (int u = 0; u < 64; ++u) {
        float h = bs1[u] + s0 * Ws1[u] + s1 * Ws1[64 + u]
                         + s2 * Ws1[128 + u] + s3 * Ws1[192 + u];
        ss += fmaxf(h, 0.f) * Ws2[u];
    }
    float p = bc2[0];
    #pragma unroll 8
    for (int u = 0; u < 128; ++u) {
        float h = bc1[u] + ss * Wc1[1024 + u];
        #pragma unroll
        for (int a = 0; a < 8; ++a) h += cc[a] * Wc1[a * 128 + u];
        p += fmaxf(h, 0.f) * Wc2[u];
    }
    out[g] = 1.f / (1.f + expf(-p));
}

// Main persistent kernel: DIRECT fp32 gather (reg-staged, bf16 convert at
// commit) — no emb table, no prep dependency for the gather.
// pairS swizzle: 16B chunk c of row r holds LOGICAL chunk (c ^ (r&7)).
__launch_bounds__(TPB, 2)
__global__ void egis_main_kernel(
    const float* __restrict__ emb,
    const int*   __restrict__ eg,
    const float* __restrict__ b1,
    const float* __restrict__ W2, const float* __restrict__ b2,
    const short* __restrict__ w1t,       // (256,256) bf16 [n][k]
    float* __restrict__ compW)           // (8, CSTRIDE)
{
    __shared__ short pairS[2][ROWS][256];  // 128 KB dbuf; pair, then relu(h)
    __shared__ short w2tS[16][264];        // W2^T bf16, rows 8-15 zero
    __shared__ int   gS[2][2][ROWS];       // [buf][g0/g1][row]

    const int tid = threadIdx.x;
    const int wv = tid >> 6, lane = tid & 63;
    const int l32 = lane & 31, lh32 = lane >> 5;
    const int axr32 = l32 & 7;
    const int l16 = lane & 15, lh = lane >> 4;
    const int axr16 = l16 & 7;

    // ---- one-time: 32 W1T cols/wave into regs; W2^T into LDS ----
    bf16x8 bReg[16];
    {
        const bf16x8* B8 = (const bf16x8*)w1t;       // 32 chunks per n-row
        const int bBase = (wv * 32 + l32) * 32 + lh32;
        #pragma unroll
        for (int ks = 0; ks < 16; ++ks) bReg[ks] = B8[bBase + ks * 2];
    }
    const float b1v = b1[wv * 32 + l32];
    const float b2v = (l16 < 8) ? b2[l16] : 0.f;

    for (int i = tid; i < 2048; i += TPB) w2tS[i & 7][i >> 3] = f2bf(W2[i]);   // k*8+n
    for (int i = tid; i < (8 * 264) / 2; i += TPB) ((int*)&w2tS[8][0])[i] = 0; // rows 8-15
    __syncthreads();

    // ---- prologue: indices + load tile t0; eg prefetch for t0+GRID ----
    int t = blockIdx.x;
    if (tid < ROWS) {
        int gid = t * ROWS + tid; if (gid >= G_CNT) gid = G_CNT - 1;
        int2 g = ((const int2*)eg)[gid];
        gS[0][0][tid] = g.x; gS[0][1][tid] = g.y;
    }
    __syncthreads();

    float4 gRegF[8][2];
    #pragma unroll 2
    for (int it = 0; it < 8; ++it) {
        int idx = it * TPB + tid;                    // row*32 + chunk
        int r = idx >> 5, rc = idx & 31;
        int gi = rc ^ (r & 7);
        int grow = (gi & 16) ? gS[0][1][r] : gS[0][0][r];
        const float4* s4 = (const float4*)(emb + (long)grow * 128 + (gi & 15) * 8);
        gRegF[it][0] = s4[0]; gRegF[it][1] = s4[1];
    }
    int2 egReg = {0, 0};
    {
        int tn = (t + GRID < NT) ? t + GRID : NT - 1;
        if (tid < ROWS) {
            int gid = tn * ROWS + tid; if (gid >= G_CNT) gid = G_CNT - 1;
            egReg = ((const int2*)eg)[gid];
        }
    }

    int cur = 0;
    while (t < NT) {
        const int nxt = cur ^ 1;

        // ---- phase A: commit staged tile t into pairS[cur]; publish gS[nxt] ----
        #pragma unroll 2
        for (int it = 0; it < 8; ++it) {
            int idx = it * TPB + tid;
            int r = idx >> 5, rc = idx & 31;
            float4 v0 = gRegF[it][0], v1 = gRegF[it][1];
            bf16x8 h;
            h[0] = f2bf(v0.x); h[1] = f2bf(v0.y); h[2] = f2bf(v0.z); h[3] = f2bf(v0.w);
            h[4] = f2bf(v1.x); h[5] = f2bf(v1.y); h[6] = f2bf(v1.z); h[7] = f2bf(v1.w);
            *(bf16x8*)&pairS[cur][r][rc * 8] = h;
        }
        if (tid < ROWS) { gS[nxt][0][tid] = egReg.x; gS[nxt][1][tid] = egReg.y; }
        __syncthreads();   // b1: commits visible; gS[nxt] visible

        // ---- phase B: issue loads for tile t+GRID; W1 GEMM on buf[cur] ----
        #pragma unroll 2
        for (int it = 0; it < 8; ++it) {
            int idx = it * TPB + tid;
            int r = idx >> 5, rc = idx & 31;
            int gi = rc ^ (r & 7);
            int grow = (gi & 16) ? gS[nxt][1][r] : gS[nxt][0][r];
            const float4* s4 = (const float4*)(emb + (long)grow * 128 + (gi & 15) * 8);
            gRegF[it][0] = s4[0]; gRegF[it][1] = s4[1];
        }
        {   // eg prefetch for t+2*GRID
            int tn2 = (t + 2 * GRID < NT) ? t + 2 * GRID : NT - 1;
            if (tid < ROWS) {
                int gid = tn2 * ROWS + tid; if (gid >= G_CNT) gid = G_CNT - 1;
                egReg = ((const int2*)eg)[gid];
            }
        }

        // W1 GEMM: wave wv -> cols wv*32..+31; 4 independent 32-row chains
        f32x16 acc0, acc1, acc2, acc3;
        #pragma unroll
        for (int i = 0; i < 16; ++i) { acc0[i] = b1v; acc1[i] = b1v; acc2[i] = b1v; acc3[i] = b1v; }
        {
            const short* r0 = &pairS[cur][ 0 + l32][0];
            const short* r1 = &pairS[cur][32 + l32][0];
            const short* r2 = &pairS[cur][64 + l32][0];
            const short* r3 = &pairS[cur][96 + l32][0];
            #pragma unroll
            for (int ks = 0; ks < 16; ++ks) {
                int off = ((ks * 2 + lh32) ^ axr32) * 8;
                bf16x8 a0 = *(const bf16x8*)(r0 + off);
                bf16x8 a1 = *(const bf16x8*)(r1 + off);
                bf16x8 a2 = *(const bf16x8*)(r2 + off);
                bf16x8 a3 = *(const bf16x8*)(r3 + off);
                acc0 = __builtin_amdgcn_mfma_f32_32x32x16_bf16(a0, bReg[ks], acc0, 0, 0, 0);
                acc1 = __builtin_amdgcn_mfma_f32_32x32x16_bf16(a1, bReg[ks], acc1, 0, 0, 0);
                acc2 = __builtin_amdgcn_mfma_f32_32x32x16_bf16(a2, bReg[ks], acc2, 0, 0, 0);
                acc3 = __builtin_amdgcn_mfma_f32_32x32x16_bf16(a3, bReg[ks], acc3, 0, 0, 0);
            }
        }
        __syncthreads();   // b2: all A-reads of buf[cur] done

        // ---- phase C: store relu(h) in place (same swizzle) ----
        {
            int col = wv * 32 + l32;
            #pragma unroll
            for (int g = 0; g < 4; ++g) {
                #pragma unroll
                for (int i = 0; i < 4; ++i) {
                    int rb = g * 8 + lh32 * 4 + i;     // D: row=(reg&3)+8*(reg>>2)+4*(lane>>5)
                    int sw0 = ((rb & 7) << 3);
                    pairS[cur][  0 + rb][col ^ sw0] = f2bf(fmaxf(acc0[g * 4 + i], 0.f));
                    pairS[cur][ 32 + rb][col ^ sw0] = f2bf(fmaxf(acc1[g * 4 + i], 0.f));
                    pairS[cur][ 64 + rb][col ^ sw0] = f2bf(fmaxf(acc2[g * 4 + i], 0.f));
                    pairS[cur][ 96 + rb][col ^ sw0] = f2bf(fmaxf(acc3[g * 4 + i], 0.f));
                }
            }
        }
        __syncthreads();   // b3: h tile visible

        // ---- phase D: comp via 16x16x32, all 8 waves; ONE float4 store/lane ----
        {
            f32x4 a2c = (f32x4){b2v, b2v, b2v, b2v};
            const short* hRow = &pairS[cur][wv * 16 + l16][0];   // (row&7)=l16&7
            const bf16x8* w2c = (const bf16x8*)&w2tS[0][0];      // 33 chunks/row
            const int wb = l16 * 33 + lh;
            #pragma unroll
            for (int ks = 0; ks < 8; ++ks) {
                bf16x8 a = *(const bf16x8*)(hRow + ((ks * 4 + lh) ^ axr16) * 8);
                bf16x8 b = w2c[wb + ks * 4];
                a2c = __builtin_amdgcn_mfma_f32_16x16x32_bf16(a, b, a2c, 0, 0, 0);
            }
            if (l16 < 8) {
                long base = (long)t * ROWS + wv * 16 + lh * 4;   // rows contiguous
                f32x4 v;
                v[0] = fmaxf(a2c[0], 0.f); v[1] = fmaxf(a2c[1], 0.f);
                v[2] = fmaxf(a2c[2], 0.f); v[3] = fmaxf(a2c[3], 0.f);
                *(f32x4*)&compW[(size_t)l16 * CSTRIDE + base] = v;
            }
        }

        cur = nxt;
        t += GRID;
    }
}

extern "C" void kernel_launch(void* const* d_in, const int* in_sizes, int n_in,
                              void* d_out, int out_size, void* d_ws, size_t ws_size,
                              hipStream_t stream) {
    const float* emb = (const float*)d_in[0];
    const int*   eg  = (const int*)d_in[1];
    const int*   ei  = (const int*)d_in[2];
    const float* W1  = (const float*)d_in[3];
    const float* b1  = (const float*)d_in[4];
    const float* W2  = (const float*)d_in[5];
    const float* b2  = (const float*)d_in[6];
    const float* Ws1 = (const float*)d_in[7];
    const float* bs1 = (const float*)d_in[8];
    const float* Ws2 = (const float*)d_in[9];
    const float* bs2 = (const float*)d_in[10];
    const float* Wc1 = (const float*)d_in[11];
    const float* bc1 = (const float*)d_in[12];
    const float* Wc2 = (const float*)d_in[13];
    const float* bc2 = (const float*)d_in[14];
    float* out = (float*)d_out;

    // ws: deg | w1t bf16 | compW f32 (8, CSTRIDE)
    char* p = (char*)d_ws;
    float* deg = (float*)p;
    size_t degB = ((size_t)NUM_NODES * 4 + 255) & ~(size_t)255;
    short* w1t = (short*)(p + degB);
    size_t w1tB = 256 * 256 * sizeof(short);
    float* compW = (float*)(p + degB + w1tB);

    // zero deg via stream memset (graph-capturable)
    hipMemsetAsync(deg, 0, (size_t)NUM_NODES * sizeof(float), stream);

    prep_fused_kernel<<<PREP_DEG_BLOCKS + PREP_W1T_BLOCKS, 256, 0, stream>>>(
        ei, deg, W1, w1t);
    egis_main_kernel<<<GRID, TPB, 0, stream>>>(
        emb, eg, b1, W2, b2, w1t, compW);
    tail_kernel<<<(G_CNT + 255) / 256, 256, 0, stream>>>(
        compW, eg, ei, deg, Ws1, bs1, Ws2, bs2, Wc1, bc1, Wc2, bc2, out);
}

// Round 30
// 449.368 us; speedup vs baseline: 1.6262x; 1.6262x over previous
//
#include <hip/hip_runtime.h>
#include <math.h>

#define E_CNT 800000
#define G_CNT 1000000
#define NUM_NODES 100000
#define ROWS 128
#define NT ((G_CNT + ROWS - 1) / ROWS)   // 7813 tiles (last tile clamped)
#define CSTRIDE ((size_t)NT * ROWS)      // compW j-plane stride (1000064)
#define GRID 256                         // 1 persistent block per CU
#define TPB 512                          // 8 waves

typedef __attribute__((ext_vector_type(8))) short bf16x8;    // 8 bf16 = 4 VGPRs
typedef __attribute__((ext_vector_type(4))) float f32x4;
typedef __attribute__((ext_vector_type(16))) float f32x16;

__device__ __forceinline__ short f2bf(float f) {
    union { float f; unsigned u; } v; v.f = f;
    unsigned r = v.u + 0x7fffu + ((v.u >> 16) & 1u);   // RNE
    return (short)(r >> 16);
}

// 2 int8 (bytes sh, sh+1 of packed) * s -> 2 bf16 packed in a uint (truncate).
__device__ __forceinline__ unsigned dq2(unsigned packed, int sh, float s) {
    int q0 = (int)((signed char)(packed >> sh));
    int q1 = (int)((signed char)(packed >> (sh + 8)));
    float f0 = (float)q0 * s, f1 = (float)q1 * s;
    union { float f; unsigned u; } a, b; a.f = f0; b.f = f1;
    return (a.u >> 16) | (b.u & 0xFFFF0000u);
}

__device__ __forceinline__ unsigned q8(float x, float inv) {
    return (unsigned)((signed char)lrintf(x * inv)) & 0xFFu;
}

// Fused prep: [0,EMB) per-ROW int8 quant (8 threads/row, 16 elems/thread,
// 32 rows/block -> 16B-coalesced both ways) | [EMB,EMB+DEG) degree | rest w1t.
// deg is zeroed by hipMemsetAsync before this launch.
#define PREP_EMB_BLOCKS 25000
#define PREP_DEG_BLOCKS 3125
#define PREP_W1T_BLOCKS 256
template <bool DOEMB>
__global__ void prep_fused_kernel(
    const float* __restrict__ emb, signed char* __restrict__ eq8,
    float* __restrict__ escale,
    const int* __restrict__ ei, float* __restrict__ deg,
    const float* __restrict__ W1, short* __restrict__ w1t)
{
    int b = blockIdx.x;
    if (DOEMB && b < PREP_EMB_BLOCKS) {
        int row = b * 32 + (threadIdx.x >> 3);        // 32 rows per block
        int sub = threadIdx.x & 7;                    // 8 threads per row
        const float4* src = (const float4*)(emb + (long)row * 128 + sub * 16);
        float4 v0 = src[0], v1 = src[1], v2 = src[2], v3 = src[3];
        float am = fmaxf(fmaxf(fmaxf(fabsf(v0.x), fabsf(v0.y)), fmaxf(fabsf(v0.z), fabsf(v0.w))),
                   fmaxf(fmaxf(fabsf(v1.x), fabsf(v1.y)), fmaxf(fabsf(v1.z), fabsf(v1.w))));
        am = fmaxf(am,
             fmaxf(fmaxf(fmaxf(fabsf(v2.x), fabsf(v2.y)), fmaxf(fabsf(v2.z), fabsf(v2.w))),
                   fmaxf(fmaxf(fabsf(v3.x), fabsf(v3.y)), fmaxf(fabsf(v3.z), fabsf(v3.w)))));
        am = fmaxf(am, __shfl_xor(am, 1));
        am = fmaxf(am, __shfl_xor(am, 2));
        am = fmaxf(am, __shfl_xor(am, 4));            // reduce over the 8-lane row group
        float inv = (am > 0.f) ? 127.f / am : 0.f;
        float scale = (am > 0.f) ? am / 127.f : 1.f;
        uint4 o;
        o.x = q8(v0.x, inv) | (q8(v0.y, inv) << 8) | (q8(v0.z, inv) << 16) | (q8(v0.w, inv) << 24);
        o.y = q8(v1.x, inv) | (q8(v1.y, inv) << 8) | (q8(v1.z, inv) << 16) | (q8(v1.w, inv) << 24);
        o.z = q8(v2.x, inv) | (q8(v2.y, inv) << 8) | (q8(v2.z, inv) << 16) | (q8(v2.w, inv) << 24);
        o.w = q8(v3.x, inv) | (q8(v3.y, inv) << 8) | (q8(v3.z, inv) << 16) | (q8(v3.w, inv) << 24);
        *(uint4*)(eq8 + (long)row * 128 + sub * 16) = o;
        if (sub == 0) escale[row] = scale;
        return;
    }
    int b2 = DOEMB ? (b - PREP_EMB_BLOCKS) : b;
    if (b2 < PREP_DEG_BLOCKS) {
        int e = b2 * 256 + threadIdx.x;
        if (e < E_CNT) {
            atomicAdd(&deg[ei[e]], 1.0f);
            atomicAdd(&deg[ei[E_CNT + e]], 1.0f);
        }
    } else {
        int t = (b2 - PREP_DEG_BLOCKS) * 256 + threadIdx.x;
        int n = t >> 8, k = t & 255;
        w1t[t] = f2bf(W1[k * 256 + n]);
    }
}

// Tail: ss (deg-MLP) + head MLP + sigmoid at full occupancy.
__global__ void tail_kernel(
    const float* __restrict__ compW,   // (8, CSTRIDE)
    const int*   __restrict__ eg,
    const int*   __restrict__ ei,
    const float* __restrict__ deg,
    const float* __restrict__ Ws1, const float* __restrict__ bs1,
    const float* __restrict__ Ws2, const float* __restrict__ bs2,
    const float* __restrict__ Wc1, const float* __restrict__ bc1,
    const float* __restrict__ Wc2, const float* __restrict__ bc2,
    float* __restrict__ out)
{
    int g = blockIdx.x * blockDim.x + threadIdx.x;
    if (g >= G_CNT) return;
    int2 gg = ((const int2*)eg)[g];
    float s0 = deg[ei[gg.x]];
    float s1 = deg[ei[E_CNT + gg.x]];
    float s2 = deg[ei[gg.y]];
    float s3 = deg[ei[E_CNT + gg.y]];
    float cc[8];
    #pragma unroll
    for (int a = 0; a < 8; ++a) cc[a] = compW[a * CSTRIDE + g];

    float ss = bs2[0];
    #pragma unroll 8
    for (int u = 0; u < 64; ++u) {
        float h = bs1[u] + s0 * Ws1[u] + s1 * Ws1[64 + u]
                         + s2 * Ws1[128 + u] + s3 * Ws1[192 + u];
        ss += fmaxf(h, 0.f) * Ws2[u];
    }
    float p = bc2[0];
    #pragma unroll 8
    for (int u = 0; u < 128; ++u) {
        float h = bc1[u] + ss * Wc1[1024 + u];
        #pragma unroll
        for (int a = 0; a < 8; ++a) h += cc[a] * Wc1[a * 128 + u];
        p += fmaxf(h, 0.f) * Wc2[u];
    }
    out[g] = 1.f / (1.f + expf(-p));
}

// Main persistent kernel. MODE 4: reg-staged int8 gather (102 MB L3-resident
// table) + per-row scale; decode at commit. MODE 1: fp32 fallback.
// pairS swizzle: 16B chunk c of row r holds LOGICAL chunk (c ^ (r&7)).
template <int MODE>
__launch_bounds__(TPB, 2)
__global__ void egis_main_kernel(
    const float* __restrict__ emb,
    const int*   __restrict__ eg,
    const float* __restrict__ b1,
    const float* __restrict__ W2, const float* __restrict__ b2,
    const short* __restrict__ w1t,       // (256,256) bf16 [n][k]
    const signed char* __restrict__ eq8, // (E,128) int8
    const float* __restrict__ escale,    // (E) per-row scale
    float* __restrict__ compW)           // (8, CSTRIDE)
{
    __shared__ short pairS[2][ROWS][256];  // 128 KB dbuf; pair, then relu(h)
    __shared__ short w2tS[16][264];        // W2^T bf16, rows 8-15 zero
    __shared__ int   gS[2][2][ROWS];       // [buf][g0/g1][row]

    const int tid = threadIdx.x;
    const int wv = tid >> 6, lane = tid & 63;
    const int l32 = lane & 31, lh32 = lane >> 5;
    const int axr32 = l32 & 7;
    const int l16 = lane & 15, lh = lane >> 4;
    const int axr16 = l16 & 7;

    // ---- one-time: 32 W1T cols/wave into regs; W2^T into LDS ----
    bf16x8 bReg[16];
    {
        const bf16x8* B8 = (const bf16x8*)w1t;       // 32 chunks per n-row
        const int bBase = (wv * 32 + l32) * 32 + lh32;
        #pragma unroll
        for (int ks = 0; ks < 16; ++ks) bReg[ks] = B8[bBase + ks * 2];
    }
    const float b1v = b1[wv * 32 + l32];
    const float b2v = (l16 < 8) ? b2[l16] : 0.f;

    for (int i = tid; i < 2048; i += TPB) w2tS[i & 7][i >> 3] = f2bf(W2[i]);   // k*8+n
    for (int i = tid; i < (8 * 264) / 2; i += TPB) ((int*)&w2tS[8][0])[i] = 0; // rows 8-15
    __syncthreads();

    // ---- prologue: indices + load tile t0; eg prefetch for t0+GRID ----
    int t = blockIdx.x;
    if (tid < ROWS) {
        int gid = t * ROWS + tid; if (gid >= G_CNT) gid = G_CNT - 1;
        int2 g = ((const int2*)eg)[gid];
        gS[0][0][tid] = g.x; gS[0][1][tid] = g.y;
    }
    __syncthreads();

    uint2 gReg8[8];        // MODE 4: 8 chunks of 8 int8
    float sReg[8];         // MODE 4: per-chunk row scale
    float4 gRegF[8][2];    // MODE 1
    if constexpr (MODE == 4) {
        #pragma unroll
        for (int it = 0; it < 8; ++it) {
            int idx = it * TPB + tid;                // row*32 + chunk
            int r = idx >> 5, rc = idx & 31;
            int gi = rc ^ (r & 7);
            int grow = (gi & 16) ? gS[0][1][r] : gS[0][0][r];
            gReg8[it] = *(const uint2*)(eq8 + (long)grow * 128 + (gi & 15) * 8);
            sReg[it] = escale[grow];
        }
    } else {
        #pragma unroll 2
        for (int it = 0; it < 8; ++it) {
            int idx = it * TPB + tid;
            int r = idx >> 5, rc = idx & 31;
            int gi = rc ^ (r & 7);
            int grow = (gi & 16) ? gS[0][1][r] : gS[0][0][r];
            const float4* s4 = (const float4*)(emb + (long)grow * 128 + (gi & 15) * 8);
            gRegF[it][0] = s4[0]; gRegF[it][1] = s4[1];
        }
    }
    int2 egReg = {0, 0};
    {
        int tn = (t + GRID < NT) ? t + GRID : NT - 1;
        if (tid < ROWS) {
            int gid = tn * ROWS + tid; if (gid >= G_CNT) gid = G_CNT - 1;
            egReg = ((const int2*)eg)[gid];
        }
    }

    int cur = 0;
    while (t < NT) {
        const int nxt = cur ^ 1;

        // ---- phase A: commit staged tile t into pairS[cur]; publish gS[nxt] ----
        if constexpr (MODE == 4) {
            #pragma unroll
            for (int it = 0; it < 8; ++it) {
                int idx = it * TPB + tid;
                int r = idx >> 5, rc = idx & 31;
                uint2 c = gReg8[it];
                float s = sReg[it];
                uint4 o;
                o.x = dq2(c.x, 0, s);
                o.y = dq2(c.x, 16, s);
                o.z = dq2(c.y, 0, s);
                o.w = dq2(c.y, 16, s);
                *(uint4*)&pairS[cur][r][rc * 8] = o;
            }
        } else {
            #pragma unroll 2
            for (int it = 0; it < 8; ++it) {
                int idx = it * TPB + tid;
                int r = idx >> 5, rc = idx & 31;
                float4 v0 = gRegF[it][0], v1 = gRegF[it][1];
                bf16x8 h;
                h[0] = f2bf(v0.x); h[1] = f2bf(v0.y); h[2] = f2bf(v0.z); h[3] = f2bf(v0.w);
                h[4] = f2bf(v1.x); h[5] = f2bf(v1.y); h[6] = f2bf(v1.z); h[7] = f2bf(v1.w);
                *(bf16x8*)&pairS[cur][r][rc * 8] = h;
            }
        }
        if (tid < ROWS) { gS[nxt][0][tid] = egReg.x; gS[nxt][1][tid] = egReg.y; }
        __syncthreads();   // b1: commits visible; gS[nxt] visible

        // ---- phase B: issue loads for tile t+GRID; W1 GEMM on buf[cur] ----
        if constexpr (MODE == 4) {
            #pragma unroll
            for (int it = 0; it < 8; ++it) {
                int idx = it * TPB + tid;
                int r = idx >> 5, rc = idx & 31;
                int gi = rc ^ (r & 7);
                int grow = (gi & 16) ? gS[nxt][1][r] : gS[nxt][0][r];
                gReg8[it] = *(const uint2*)(eq8 + (long)grow * 128 + (gi & 15) * 8);
                sReg[it] = escale[grow];
            }
        } else {
            #pragma unroll 2
            for (int it = 0; it < 8; ++it) {
                int idx = it * TPB + tid;
                int r = idx >> 5, rc = idx & 31;
                int gi = rc ^ (r & 7);
                int grow = (gi & 16) ? gS[nxt][1][r] : gS[nxt][0][r];
                const float4* s4 = (const float4*)(emb + (long)grow * 128 + (gi & 15) * 8);
                gRegF[it][0] = s4[0]; gRegF[it][1] = s4[1];
            }
        }
        {   // eg prefetch for t+2*GRID
            int tn2 = (t + 2 * GRID < NT) ? t + 2 * GRID : NT - 1;
            if (tid < ROWS) {
                int gid = tn2 * ROWS + tid; if (gid >= G_CNT) gid = G_CNT - 1;
                egReg = ((const int2*)eg)[gid];
            }
        }

        // W1 GEMM: wave wv -> cols wv*32..+31; 4 independent 32-row chains
        f32x16 acc0, acc1, acc2, acc3;
        #pragma unroll
        for (int i = 0; i < 16; ++i) { acc0[i] = b1v; acc1[i] = b1v; acc2[i] = b1v; acc3[i] = b1v; }
        {
            const short* r0 = &pairS[cur][ 0 + l32][0];
            const short* r1 = &pairS[cur][32 + l32][0];
            const short* r2 = &pairS[cur][64 + l32][0];
            const short* r3 = &pairS[cur][96 + l32][0];
            #pragma unroll
            for (int ks = 0; ks < 16; ++ks) {
                int off = ((ks * 2 + lh32) ^ axr32) * 8;
                bf16x8 a0 = *(const bf16x8*)(r0 + off);
                bf16x8 a1 = *(const bf16x8*)(r1 + off);
                bf16x8 a2 = *(const bf16x8*)(r2 + off);
                bf16x8 a3 = *(const bf16x8*)(r3 + off);
                acc0 = __builtin_amdgcn_mfma_f32_32x32x16_bf16(a0, bReg[ks], acc0, 0, 0, 0);
                acc1 = __builtin_amdgcn_mfma_f32_32x32x16_bf16(a1, bReg[ks], acc1, 0, 0, 0);
                acc2 = __builtin_amdgcn_mfma_f32_32x32x16_bf16(a2, bReg[ks], acc2, 0, 0, 0);
                acc3 = __builtin_amdgcn_mfma_f32_32x32x16_bf16(a3, bReg[ks], acc3, 0, 0, 0);
            }
        }
        __syncthreads();   // b2: all A-reads of buf[cur] done

        // ---- phase C: store relu(h) in place (same swizzle) ----
        {
            int col = wv * 32 + l32;
            #pragma unroll
            for (int g = 0; g < 4; ++g) {
                #pragma unroll
                for (int i = 0; i < 4; ++i) {
                    int rb = g * 8 + lh32 * 4 + i;     // D: row=(reg&3)+8*(reg>>2)+4*(lane>>5)
                    int sw0 = ((rb & 7) << 3);
                    pairS[cur][  0 + rb][col ^ sw0] = f2bf(fmaxf(acc0[g * 4 + i], 0.f));
                    pairS[cur][ 32 + rb][col ^ sw0] = f2bf(fmaxf(acc1[g * 4 + i], 0.f));
                    pairS[cur][ 64 + rb][col ^ sw0] = f2bf(fmaxf(acc2[g * 4 + i], 0.f));
                    pairS[cur][ 96 + rb][col ^ sw0] = f2bf(fmaxf(acc3[g * 4 + i], 0.f));
                }
            }
        }
        __syncthreads();   // b3: h tile visible

        // ---- phase D: comp via 16x16x32, all 8 waves; ONE float4 store/lane ----
        {
            f32x4 a2c = (f32x4){b2v, b2v, b2v, b2v};
            const short* hRow = &pairS[cur][wv * 16 + l16][0];   // (row&7)=l16&7
            const bf16x8* w2c = (const bf16x8*)&w2tS[0][0];      // 33 chunks/row
            const int wb = l16 * 33 + lh;
            #pragma unroll
            for (int ks = 0; ks < 8; ++ks) {
                bf16x8 a = *(const bf16x8*)(hRow + ((ks * 4 + lh) ^ axr16) * 8);
                bf16x8 b = w2c[wb + ks * 4];
                a2c = __builtin_amdgcn_mfma_f32_16x16x32_bf16(a, b, a2c, 0, 0, 0);
            }
            if (l16 < 8) {
                long base = (long)t * ROWS + wv * 16 + lh * 4;   // rows contiguous
                f32x4 v;
                v[0] = fmaxf(a2c[0], 0.f); v[1] = fmaxf(a2c[1], 0.f);
                v[2] = fmaxf(a2c[2], 0.f); v[3] = fmaxf(a2c[3], 0.f);
                *(f32x4*)&compW[(size_t)l16 * CSTRIDE + base] = v;
            }
        }

        cur = nxt;
        t += GRID;
    }
}

extern "C" void kernel_launch(void* const* d_in, const int* in_sizes, int n_in,
                              void* d_out, int out_size, void* d_ws, size_t ws_size,
                              hipStream_t stream) {
    const float* emb = (const float*)d_in[0];
    const int*   eg  = (const int*)d_in[1];
    const int*   ei  = (const int*)d_in[2];
    const float* W1  = (const float*)d_in[3];
    const float* b1  = (const float*)d_in[4];
    const float* W2  = (const float*)d_in[5];
    const float* b2  = (const float*)d_in[6];
    const float* Ws1 = (const float*)d_in[7];
    const float* bs1 = (const float*)d_in[8];
    const float* Ws2 = (const float*)d_in[9];
    const float* bs2 = (const float*)d_in[10];
    const float* Wc1 = (const float*)d_in[11];
    const float* bc1 = (const float*)d_in[12];
    const float* Wc2 = (const float*)d_in[13];
    const float* bc2 = (const float*)d_in[14];
    float* out = (float*)d_out;

    // ws: deg | w1t bf16 | compW f32 (8, CSTRIDE) | escale f32 | eq8 int8
    char* p = (char*)d_ws;
    float* deg = (float*)p;
    size_t degB = ((size_t)NUM_NODES * 4 + 255) & ~(size_t)255;
    short* w1t = (short*)(p + degB);
    size_t w1tB = 256 * 256 * sizeof(short);
    float* compW = (float*)(p + degB + w1tB);
    size_t compB = 8 * CSTRIDE * sizeof(float);   // ~32 MB
    float* escale = (float*)(p + degB + w1tB + compB);
    size_t escB = (size_t)E_CNT * sizeof(float);  // 3.2 MB
    signed char* eq8 = (signed char*)(p + degB + w1tB + compB + escB);
    size_t embB = (size_t)E_CNT * 128;            // 102.4 MB

    int mode = (ws_size >= degB + w1tB + compB + escB + embB) ? 4 : 1;

    // zero deg via stream memset (graph-capturable) — one fewer kernel launch
    hipMemsetAsync(deg, 0, (size_t)NUM_NODES * sizeof(float), stream);

    if (mode == 4) {
        prep_fused_kernel<true><<<PREP_EMB_BLOCKS + PREP_DEG_BLOCKS + PREP_W1T_BLOCKS,
                                  256, 0, stream>>>(emb, eq8, escale, ei, deg, W1, w1t);
        egis_main_kernel<4><<<GRID, TPB, 0, stream>>>(
            emb, eg, b1, W2, b2, w1t, eq8, escale, compW);
    } else {
        prep_fused_kernel<false><<<PREP_DEG_BLOCKS + PREP_W1T_BLOCKS,
                                   256, 0, stream>>>(emb, (signed char*)nullptr, (float*)nullptr,
                                                     ei, deg, W1, w1t);
        egis_main_kernel<1><<<GRID, TPB, 0, stream>>>(
            emb, eg, b1, W2, b2, w1t, (const signed char*)nullptr, (const float*)nullptr, compW);
    }
    tail_kernel<<<(G_CNT + 255) / 256, 256, 0, stream>>>(
        compW, eg, ei, deg, Ws1, bs1, Ws2, bs2, Wc1, bc1, Wc2, bc2, out);
}